// Round 3
// baseline (127.917 us; speedup 1.0000x reference)
//
#include <hip/hip_runtime.h>
#include <stdint.h>

// ============================================================================
// SpikingUnifiedCoreFlow: 4-layer LIF chain, T=32, exact fixed-point via i8.
//
// R9: R8's ds_read dedup RESTORED INTO R7's 2-phase pacing (R8 post-mortem:
// dedup was right, single-phase pacing was wrong -- it serialized all 4
// staged slices in front of each MFMA burst).
// Waves = sg(2) x mw(2) x nw(2); each wave owns TWO 32-row M-tiles (A is
// register-resident bitmasks) but only 2 of 4 digit slices -> each B
// ds_read_b128 feeds 2 MFMAs (LDS-read pipe halved vs R7).
// Stage groups: H0 = global slices {0,2} (phase-1 operands for sg=0/1),
// H1 = {1,3} (phase-2 operands). Per phase: 4 ds_read + 8 MFMA + 2 stage
// issues -- R7's proven rhythm. Issue order H0 -> A -> H1; counted waits:
// P1 vmcnt(2), P2 vmcnt(4) (tail 0). Slice halves recombined exactly in
// the epilogue via swizzled LDS exchange (integer, bit-identical).
// Workspace: planes 16MB @0 | Amask0 512KB @16777216 | Amask1 @17301504
// ============================================================================

typedef __attribute__((ext_vector_type(4)))  int   i32x4;
typedef __attribute__((ext_vector_type(16))) int   i32x16;
typedef __attribute__((ext_vector_type(4)))  float f32x4;

#define SCALE_F 4294967296.0f   // 2^32
#define NSL 4

__device__ __forceinline__ void gload16(const void* g, void* l) {
    __builtin_amdgcn_global_load_lds(
        (const __attribute__((address_space(1))) void*)g,
        (__attribute__((address_space(3))) void*)l, 16, 0, 0);
}

// 16 bits -> 16 i8 bytes (0/1): nibble spread, no carries (disjoint shifts)
__device__ __forceinline__ i32x4 expand16(unsigned int f) {
    i32x4 r;
    #pragma unroll
    for (int d = 0; d < 4; ++d)
        r[d] = (int)((((f >> (4 * d)) & 0xFu) * 0x00204081u) & 0x01010101u);
    return r;
}

// ----------------------------------------------------- prep (merged) --------
// blocks 0..4095: digit decomposition; blocks 4096..4607: encode+transpose
__global__ void k_prep(const float* __restrict__ x, const float* __restrict__ w,
                       uint32_t* __restrict__ Am, signed char* __restrict__ planes) {
    if (blockIdx.x < 4096) {
        // ---- digits: 1M threads, 4 weights each ----
        int tid = blockIdx.x * 256 + threadIdx.x;
        int l = tid >> 18;
        int rest4 = (tid & 0x3FFFF) << 2;
        f32x4 wv = *reinterpret_cast<const f32x4*>(w + ((size_t)l << 20) + rest4);
        long long q[4];
        #pragma unroll
        for (int i = 0; i < 4; ++i) q[i] = llrintf(wv[i] * SCALE_F);  // exact
        #pragma unroll
        for (int s = 0; s < NSL; ++s) {
            uint32_t pack = 0;
            #pragma unroll
            for (int i = 0; i < 4; ++i) {
                int d = (int)(signed char)((unsigned char)(q[i] & 255));
                q[i] = (q[i] - d) >> 8;
                pack |= ((uint32_t)(unsigned char)d) << (8 * i);
            }
            *reinterpret_cast<uint32_t*>(planes + (((size_t)(l * NSL + s)) << 20) + rest4) = pack;
        }
    } else {
        // ---- encode+transpose: 2048 waves ----
        const int wid  = ((blockIdx.x - 4096) * 256 + threadIdx.x) >> 6;
        const int lane = threadIdx.x & 63;
        const int b = wid >> 4, kc = wid & 15;
        float v = x[b * 1024 + kc * 64 + lane];
        int N = (int)rintf(v * 32.0f);                 // jnp.round = half-to-even
        uint32_t bits = 0;
        if (N >= 32) {
            bits = 0xFFFFFFFFu;
        } else if (N > 0) {
            float spacing = 32.0f / (float)N;
            #pragma unroll
            for (int t = 0; t < 32; ++t) {
                float fm = fmodf((float)t, spacing);   // exact in IEEE
                if (fm < 1.0f) bits |= (1u << t);
            }
        }
        uint32_t cap = 0;
        #pragma unroll
        for (int t = 0; t < 32; ++t) {
            unsigned long long bal = __ballot((bits >> t) & 1u);
            if (lane == t)      cap = (uint32_t)bal;          // lanes 0..31: lo
            if (lane == t + 32) cap = (uint32_t)(bal >> 32);  // lanes 32..63: hi
        }
        const int t = lane & 31, ww = lane >> 5;
        Am[(size_t)(b * 32 + t) * 32 + kc * 2 + ww] = cap;
    }
}

// ----------------------------------------------------------------- fused ----
// LDS/buf (32KB): slice s @ s*8192 : [row 0..63][8 slots][16B]; physical slot
// q holds GLOBAL k-granule q ^ (row&7) (source-pre-swizzle, conflict-free).
__global__ __launch_bounds__(512, 4) void k_fused(
        const uint32_t* __restrict__ Am,
        const signed char* __restrict__ planes,
        const float* __restrict__ th,
        uint32_t* __restrict__ AmNext,     // null on last layer
        float* __restrict__ out,           // null except last layer
        int layer) {
    __shared__ alignas(16) signed char lds[2][32768];

    const int tid  = threadIdx.x;
    const int lane = tid & 63;
    const int wave = tid >> 6;             // 0..7
    const int sg   = wave >> 2;            // 0..1 : slice group (slices sg*2, sg*2+1)
    const int mw   = (wave >> 1) & 1;      // 0..1 : 64-row group
    const int nw   = wave & 1;             // 0..1 : 32-col half
    const int lr   = lane & 31;
    const int hi   = lane >> 5;

    // bijective XCD mapping: each XCD owns 2 n-panels (512KB B, L2-resident)
    const int xc = blockIdx.x & 7, q = blockIdx.x >> 3;
    const int nTile = xc * 2 + (q & 1);    // 0..15
    const int mTile = q >> 1;              // 0..31
    const int mBase = mTile * 128, nBase = nTile * 64;

    // B staging sources: 4 units(16B)/thread/chunk, source-pre-swizzled
    const signed char* srcB[NSL];
    {
        const int r0 = tid >> 3, qs = tid & 7;
        const int sw0 = (qs ^ (r0 & 7)) * 16;
        #pragma unroll
        for (int s = 0; s < NSL; ++s)
            srcB[s] = planes + (((size_t)(layer * NSL + s)) << 20)
                    + (size_t)(nBase + r0) * 1024 + sw0;
    }
    // A bitmask row pointers for the wave's two M-tiles (u32; row stride 128B)
    const uint32_t* aRow0 = Am + (size_t)(mBase + mw * 64 + lr) * 32;
    const uint32_t* aRow1 = aRow0 + 32 * 32;

    // per-thread B read addresses (dynamic part); slice base added separately
    int baddr[4];
    {
        const int brow = nw * 32 + lr;
        #pragma unroll
        for (int ks = 0; ks < 4; ++ks)
            baddr[ks] = brow * 128 + (((ks * 2 + hi) ^ (brow & 7)) * 16);
    }
    const int sb1 = sg * 16384;            // phase-1 slice base (global slice sg*2)
    const int sb2 = sb1 + 8192;            // phase-2 slice base (global slice sg*2+1)

    i32x16 acc[2][2];                      // [Mt][slice-local]
    #pragma unroll
    for (int m = 0; m < 2; ++m)
        #pragma unroll
        for (int s = 0; s < 2; ++s)
            #pragma unroll
            for (int r = 0; r < 16; ++r) acc[m][s][r] = 0;

    auto H0 = [&](int buf, int c) {        // global slices {0,2}: phase-1 operands
        const int ko = c * 128;
        gload16(srcB[0] + ko, &lds[buf][0]     + tid * 16);
        gload16(srcB[2] + ko, &lds[buf][16384] + tid * 16);
    };
    auto H1 = [&](int buf, int c) {        // global slices {1,3}: phase-2 operands
        const int ko = c * 128;
        gload16(srcB[1] + ko, &lds[buf][8192]  + tid * 16);
        gload16(srcB[3] + ko, &lds[buf][24576] + tid * 16);
    };

    i32x4 amr0[2], amr1[2];                // per-chunk A bits, ping-pong
    H0(0, 0);
    amr0[0] = *reinterpret_cast<const i32x4*>(aRow0);
    amr1[0] = *reinterpret_cast<const i32x4*>(aRow1);
    H1(0, 0);

    #pragma unroll
    for (int c = 0; c < 8; ++c) {
        const int buf = c & 1;
        const signed char* lb = &lds[buf][0];

        // ---- phase 1: need H0(c)+A(c); H1(c)^2 stays in flight ----
        asm volatile("s_waitcnt vmcnt(2)" ::: "memory");
        __builtin_amdgcn_s_barrier();
        asm volatile("" ::: "memory");

        if (c + 1 < 8) {
            H0(buf ^ 1, c + 1);
            amr0[(c + 1) & 1] = *reinterpret_cast<const i32x4*>(aRow0 + (c + 1) * 4);
            amr1[(c + 1) & 1] = *reinterpret_cast<const i32x4*>(aRow1 + (c + 1) * 4);
        }

        __builtin_amdgcn_s_setprio(1);
        #pragma unroll
        for (int ks = 0; ks < 4; ++ks) {
            i32x4 af0 = expand16((((unsigned)amr0[c & 1][ks]) >> (16 * hi)) & 0xFFFFu);
            i32x4 af1 = expand16((((unsigned)amr1[c & 1][ks]) >> (16 * hi)) & 0xFFFFu);
            i32x4 bf = *reinterpret_cast<const i32x4*>(lb + sb1 + baddr[ks]);
            acc[0][0] = __builtin_amdgcn_mfma_i32_32x32x32_i8(af0, bf, acc[0][0], 0, 0, 0);
            acc[1][0] = __builtin_amdgcn_mfma_i32_32x32x32_i8(af1, bf, acc[1][0], 0, 0, 0);
        }
        __builtin_amdgcn_s_setprio(0);

        // ---- phase 2: need H1(c); H0(c+1)^2+A(c+1)^2 stay in flight ----
        if (c + 1 < 8) asm volatile("s_waitcnt vmcnt(4)" ::: "memory");
        else           asm volatile("s_waitcnt vmcnt(0)" ::: "memory");
        __builtin_amdgcn_s_barrier();
        asm volatile("" ::: "memory");

        if (c + 1 < 8) H1(buf ^ 1, c + 1);

        __builtin_amdgcn_s_setprio(1);
        #pragma unroll
        for (int ks = 0; ks < 4; ++ks) {
            i32x4 af0 = expand16((((unsigned)amr0[c & 1][ks]) >> (16 * hi)) & 0xFFFFu);
            i32x4 af1 = expand16((((unsigned)amr1[c & 1][ks]) >> (16 * hi)) & 0xFFFFu);
            i32x4 bf = *reinterpret_cast<const i32x4*>(lb + sb2 + baddr[ks]);
            acc[0][1] = __builtin_amdgcn_mfma_i32_32x32x32_i8(af0, bf, acc[0][1], 0, 0, 0);
            acc[1][1] = __builtin_amdgcn_mfma_i32_32x32x32_i8(af1, bf, acc[1][1], 0, 0, 0);
        }
        __builtin_amdgcn_s_setprio(0);
    }

    // ---- epilogue ----------------------------------------------------------
    // partials: v(Mt) = acc[Mt][0] + (acc[Mt][1]<<8); full = vsg0 + (vsg1<<16).
    // Exchange the "other" Mt with the partner slice-group wave (exact int).
    long long pKeep[16], pSend[16];
    #pragma unroll
    for (int r = 0; r < 16; ++r) {
        long long v0 = (long long)acc[0][0][r] + ((long long)acc[0][1][r] << 8);
        long long v1 = (long long)acc[1][0][r] + ((long long)acc[1][1][r] << 8);
        pKeep[r] = sg ? v1 : v0;           // Mt = sg stays with this wave
        pSend[r] = sg ? v0 : v1;           // Mt = sg^1 goes to partner
    }

    signed char* ex = &lds[0][0];
    const int pr = (mw * 2 + nw);
    const int reg_w = (pr * 2 + sg) * 8192;
    const int reg_r = (pr * 2 + (sg ^ 1)) * 8192;
    #pragma unroll
    for (int u = 0; u < 8; ++u) {          // swizzled: conflict-free b128
        i32x4 wv;
        long long a = pSend[2 * u], b = pSend[2 * u + 1];
        wv[0] = (int)a; wv[1] = (int)(a >> 32);
        wv[2] = (int)b; wv[3] = (int)(b >> 32);
        *reinterpret_cast<i32x4*>(ex + reg_w + lane * 128 + ((u ^ (lane & 7)) * 16)) = wv;
    }
    __syncthreads();
    long long tot[16];
    #pragma unroll
    for (int u = 0; u < 8; ++u) {
        i32x4 v = *reinterpret_cast<const i32x4*>(
                ex + reg_r + lane * 128 + ((u ^ (lane & 7)) * 16));
        long long a = ((long long)v[1] << 32) | (uint32_t)v[0];
        long long b = ((long long)v[3] << 32) | (uint32_t)v[2];
        tot[2 * u]     = sg ? (pKeep[2 * u]     << 16) + a : pKeep[2 * u]     + (a << 16);
        tot[2 * u + 1] = sg ? (pKeep[2 * u + 1] << 16) + b : pKeep[2 * u + 1] + (b << 16);
    }

    // LIF recurrence on ALL lanes (hi halves compute identical bits).
    // C/D 32x32: col=lane&31, row(t) = (r&3) + 8*(r>>2) + 4*hi  [m74/m101]
    const long long TH = llrintf(th[layer] * SCALE_F);
    const int batch = mTile * 4 + mw * 2 + sg;
    uint32_t bits = 0;
    long long mmem = 0;
    #pragma unroll
    for (int half = 0; half < 2; ++half) {
        long long own_[8], par[8];
        #pragma unroll
        for (int r = 0; r < 8; ++r) own_[r] = tot[half * 8 + r];
        #pragma unroll
        for (int r = 0; r < 8; ++r) {
            int plo = __shfl((int)(uint32_t)own_[r], lane ^ 32, 64);
            int phi = __shfl((int)(own_[r] >> 32), lane ^ 32, 64);
            par[r] = ((long long)phi << 32) | (uint32_t)plo;
        }
        #pragma unroll
        for (int tq = 0; tq < 16; ++tq) {   // t = half*16 + tq
            const int idx = (tq >> 3) * 4 + (tq & 3);
            const int usePar = ((tq >> 2) & 1) ^ hi;
            long long v = usePar ? par[idx] : own_[idx];
            mmem += v;
            if (mmem > TH) { mmem -= TH; bits |= (1u << (half * 16 + tq)); }
        }
    }

    if (AmNext) {
        uint32_t cap = 0;
        #pragma unroll
        for (int t = 0; t < 32; ++t) {
            unsigned long long bal = __ballot((bits >> t) & 1u);
            if (lane == t) cap = (uint32_t)bal;   // lo32 = cols of this nw half
        }
        if (hi == 0)
            AmNext[(size_t)(batch * 32 + lr) * 32 + nTile * 2 + nw] = cap;
    } else if (hi == 0) {
        out[batch * 1024 + nBase + nw * 32 + lr] = (float)__popc(bits) * 0.03125f;
    }
}

// ---------------------------------------------------------------- launch ----
extern "C" void kernel_launch(void* const* d_in, const int* in_sizes, int n_in,
                              void* d_out, int out_size, void* d_ws, size_t ws_size,
                              hipStream_t stream) {
    const float* x  = (const float*)d_in[0];
    const float* w  = (const float*)d_in[1];
    const float* th = (const float*)d_in[2];
    float* out = (float*)d_out;
    char* ws = (char*)d_ws;

    signed char* planes = (signed char*)(ws);                 // 16 MB
    uint32_t*    Am0    = (uint32_t*)(ws + 16777216);         // 512 KB
    uint32_t*    Am1    = (uint32_t*)(ws + 17301504);         // 512 KB

    k_prep<<<4608, 256, 0, stream>>>(x, w, Am0, planes);

    uint32_t* Ain = Am0;
    uint32_t* Anx = Am1;
    for (int l = 0; l < 4; ++l) {
        k_fused<<<512, 512, 0, stream>>>(Ain, planes, th,
                                         (l < 3) ? Anx : nullptr,
                                         (l == 3) ? out : nullptr, l);
        uint32_t* tmp = Ain; Ain = Anx; Anx = tmp;
    }
}

// Round 4
// 104.962 us; speedup vs baseline: 1.2187x; 1.2187x over previous
//
#include <hip/hip_runtime.h>
#include <stdint.h>

// ============================================================================
// SpikingUnifiedCoreFlow: 4-layer LIF chain, T=32, exact fixed-point via i8.
//
// R10: revert to R7's proven k_fused structure (dedup direction abandoned:
// R8/R9 showed the slice-split's mandatory exchange epilogue + doubled
// expand16 VALU outweigh the halved ds_read traffic). Changes vs R7:
//  (1) merged k_prep kept (launch-gap save, not implicated in regressions);
//  (2) deeper H1 prefetch: H0(c+1)+A(c+1)+H1(c+1) all issued in P1, making
//      P2 a pure {wait, barrier, MFMA} phase -- shorter P2 critical segment
//      and a full extra phase of flight for H1. Waits: P1 vmcnt(2) (leaves
//      H1(c)^2), P2 vmcnt(5) (leaves c+1's 5 loads), tail 0.
// Waves = mw(4) x nw(2); per wave: 1 M-tile, all 4 slices, acc = 64 VGPRs;
// af[4] expanded once per chunk in P1, reused in P2.
// Workspace: planes 16MB @0 | Amask0 512KB @16777216 | Amask1 @17301504
// ============================================================================

typedef __attribute__((ext_vector_type(4)))  int   i32x4;
typedef __attribute__((ext_vector_type(16))) int   i32x16;
typedef __attribute__((ext_vector_type(4)))  float f32x4;

#define SCALE_F 4294967296.0f   // 2^32
#define NSL 4

__device__ __forceinline__ void gload16(const void* g, void* l) {
    __builtin_amdgcn_global_load_lds(
        (const __attribute__((address_space(1))) void*)g,
        (__attribute__((address_space(3))) void*)l, 16, 0, 0);
}

// 16 bits -> 16 i8 bytes (0/1): nibble spread, no carries (disjoint shifts)
__device__ __forceinline__ i32x4 expand16(unsigned int f) {
    i32x4 r;
    #pragma unroll
    for (int d = 0; d < 4; ++d)
        r[d] = (int)((((f >> (4 * d)) & 0xFu) * 0x00204081u) & 0x01010101u);
    return r;
}

// ----------------------------------------------------- prep (merged) --------
// blocks 0..4095: digit decomposition; blocks 4096..4607: encode+transpose
__global__ void k_prep(const float* __restrict__ x, const float* __restrict__ w,
                       uint32_t* __restrict__ Am, signed char* __restrict__ planes) {
    if (blockIdx.x < 4096) {
        // ---- digits: 1M threads, 4 weights each ----
        int tid = blockIdx.x * 256 + threadIdx.x;
        int l = tid >> 18;
        int rest4 = (tid & 0x3FFFF) << 2;
        f32x4 wv = *reinterpret_cast<const f32x4*>(w + ((size_t)l << 20) + rest4);
        long long q[4];
        #pragma unroll
        for (int i = 0; i < 4; ++i) q[i] = llrintf(wv[i] * SCALE_F);  // exact
        #pragma unroll
        for (int s = 0; s < NSL; ++s) {
            uint32_t pack = 0;
            #pragma unroll
            for (int i = 0; i < 4; ++i) {
                int d = (int)(signed char)((unsigned char)(q[i] & 255));
                q[i] = (q[i] - d) >> 8;
                pack |= ((uint32_t)(unsigned char)d) << (8 * i);
            }
            *reinterpret_cast<uint32_t*>(planes + (((size_t)(l * NSL + s)) << 20) + rest4) = pack;
        }
    } else {
        // ---- encode+transpose: 2048 waves ----
        const int wid  = ((blockIdx.x - 4096) * 256 + threadIdx.x) >> 6;
        const int lane = threadIdx.x & 63;
        const int b = wid >> 4, kc = wid & 15;
        float v = x[b * 1024 + kc * 64 + lane];
        int N = (int)rintf(v * 32.0f);                 // jnp.round = half-to-even
        uint32_t bits = 0;
        if (N >= 32) {
            bits = 0xFFFFFFFFu;
        } else if (N > 0) {
            float spacing = 32.0f / (float)N;
            #pragma unroll
            for (int t = 0; t < 32; ++t) {
                float fm = fmodf((float)t, spacing);   // exact in IEEE
                if (fm < 1.0f) bits |= (1u << t);
            }
        }
        uint32_t cap = 0;
        #pragma unroll
        for (int t = 0; t < 32; ++t) {
            unsigned long long bal = __ballot((bits >> t) & 1u);
            if (lane == t)      cap = (uint32_t)bal;          // lanes 0..31: lo
            if (lane == t + 32) cap = (uint32_t)(bal >> 32);  // lanes 32..63: hi
        }
        const int t = lane & 31, ww = lane >> 5;
        Am[(size_t)(b * 32 + t) * 32 + kc * 2 + ww] = cap;
    }
}

// ----------------------------------------------------------------- fused ----
// LDS/buf (32KB): slice s @ s*8192 : [row 0..63][8 slots][16B]; physical slot
// q holds GLOBAL k-granule q ^ (row&7) (source-pre-swizzle, conflict-free).
__global__ __launch_bounds__(512, 4) void k_fused(
        const uint32_t* __restrict__ Am,
        const signed char* __restrict__ planes,
        const float* __restrict__ th,
        uint32_t* __restrict__ AmNext,     // null on last layer
        float* __restrict__ out,           // null except last layer
        int layer) {
    __shared__ alignas(16) signed char lds[2][32768];

    const int tid  = threadIdx.x;
    const int lane = tid & 63;
    const int wave = tid >> 6;             // 0..7
    const int mw   = wave >> 1;            // 0..3 : 32-row batch tile
    const int nw   = wave & 1;             // 0..1 : 32-col half
    const int lr   = lane & 31;
    const int hi   = lane >> 5;

    // bijective XCD mapping: each XCD owns 2 n-panels (512KB B, L2-resident)
    const int xc = blockIdx.x & 7, q = blockIdx.x >> 3;
    const int nTile = xc * 2 + (q & 1);    // 0..15
    const int mTile = q >> 1;              // 0..31
    const int mBase = mTile * 128, nBase = nTile * 64;

    // B staging sources: 4 units(16B)/thread/chunk, source-pre-swizzled
    const signed char* srcB[NSL];
    {
        const int r0 = tid >> 3, qs = tid & 7;
        const int sw0 = (qs ^ (r0 & 7)) * 16;
        #pragma unroll
        for (int s = 0; s < NSL; ++s)
            srcB[s] = planes + (((size_t)(layer * NSL + s)) << 20)
                    + (size_t)(nBase + r0) * 1024 + sw0;
    }
    // A bitmask row pointer (u32 words; row stride 32 words = 128B)
    const uint32_t* aRow = Am + (size_t)(mBase + mw * 32 + lr) * 32;

    // per-thread B read addresses (dynamic part); slice base added separately
    int baddr[4];
    {
        const int brow = nw * 32 + lr;
        #pragma unroll
        for (int ks = 0; ks < 4; ++ks)
            baddr[ks] = brow * 128 + (((ks * 2 + hi) ^ (brow & 7)) * 16);
    }

    i32x16 acc[NSL];
    #pragma unroll
    for (int s = 0; s < NSL; ++s)
        #pragma unroll
        for (int r = 0; r < 16; ++r) acc[s][r] = 0;

    auto H0 = [&](int buf, int c) {        // slices 0,1 : 2 units/thread
        const int ko = c * 128;
        gload16(srcB[0] + ko, &lds[buf][0]    + tid * 16);
        gload16(srcB[1] + ko, &lds[buf][8192] + tid * 16);
    };
    auto H1 = [&](int buf, int c) {        // slices 2,3 : 2 units/thread
        const int ko = c * 128;
        gload16(srcB[2] + ko, &lds[buf][16384] + tid * 16);
        gload16(srcB[3] + ko, &lds[buf][24576] + tid * 16);
    };

    i32x4 amr[2];                          // per-chunk A bits, ping-pong
    H0(0, 0);
    amr[0] = *reinterpret_cast<const i32x4*>(aRow);
    H1(0, 0);

    #pragma unroll
    for (int c = 0; c < 8; ++c) {
        const int buf = c & 1;
        const signed char* lb = &lds[buf][0];

        // ---- phase 1: need H0(c)+A(c); H1(c)^2 stays in flight ----
        asm volatile("s_waitcnt vmcnt(2)" ::: "memory");
        __builtin_amdgcn_s_barrier();
        asm volatile("" ::: "memory");

        if (c + 1 < 8) {                   // issue ALL of chunk c+1 here:
            H0(buf ^ 1, c + 1);            // P2 becomes pure compute, and
            amr[(c + 1) & 1] = *reinterpret_cast<const i32x4*>(aRow + (c + 1) * 4);
            H1(buf ^ 1, c + 1);            // H1 gets a full extra phase of flight
        }

        i32x4 af[4];                       // A fragments, reused in phase 2
        __builtin_amdgcn_s_setprio(1);
        #pragma unroll
        for (int ks = 0; ks < 4; ++ks) {
            af[ks] = expand16((((unsigned)amr[c & 1][ks]) >> (16 * hi)) & 0xFFFFu);
            #pragma unroll
            for (int s = 0; s < 2; ++s) {
                i32x4 bf = *reinterpret_cast<const i32x4*>(lb + s * 8192 + baddr[ks]);
                acc[s] = __builtin_amdgcn_mfma_i32_32x32x32_i8(af[ks], bf, acc[s], 0, 0, 0);
            }
        }
        __builtin_amdgcn_s_setprio(0);

        // ---- phase 2: need H1(c); c+1's 5 loads stay in flight ----
        if (c + 1 < 8) asm volatile("s_waitcnt vmcnt(5)" ::: "memory");
        else           asm volatile("s_waitcnt vmcnt(0)" ::: "memory");
        __builtin_amdgcn_s_barrier();
        asm volatile("" ::: "memory");

        __builtin_amdgcn_s_setprio(1);
        #pragma unroll
        for (int ks = 0; ks < 4; ++ks) {
            #pragma unroll
            for (int s = 0; s < 2; ++s) {
                i32x4 bf = *reinterpret_cast<const i32x4*>(lb + (2 + s) * 8192 + baddr[ks]);
                acc[2 + s] = __builtin_amdgcn_mfma_i32_32x32x32_i8(af[ks], bf, acc[2 + s], 0, 0, 0);
            }
        }
        __builtin_amdgcn_s_setprio(0);
    }

    // epilogue: combine slices -> int64, swap halves, LIF recurrence on ALL
    // lanes (hi halves compute identical bits), ballot-transpose to next mask.
    // C/D 32x32: col=lane&31, row(t) = (r&3) + 8*(r>>2) + 4*hi  [m74/m101]
    const long long TH = llrintf(th[layer] * SCALE_F);
    const int batch = mTile * 4 + mw;
    uint32_t bits = 0;
    long long mmem = 0;
    #pragma unroll
    for (int half = 0; half < 2; ++half) {
        long long own[8], par[8];
        #pragma unroll
        for (int r = 0; r < 8; ++r) {
            long long v = 0;
            #pragma unroll
            for (int s = 0; s < NSL; ++s)
                v += ((long long)acc[s][half * 8 + r]) << (8 * s);
            own[r] = v;
        }
        #pragma unroll
        for (int r = 0; r < 8; ++r) {
            int plo = __shfl((int)(uint32_t)own[r], lane ^ 32, 64);
            int phi = __shfl((int)(own[r] >> 32), lane ^ 32, 64);
            par[r] = ((long long)phi << 32) | (uint32_t)plo;
        }
        #pragma unroll
        for (int tq = 0; tq < 16; ++tq) {   // t = half*16 + tq
            const int idx = (tq >> 3) * 4 + (tq & 3);
            const int usePar = ((tq >> 2) & 1) ^ hi;
            long long v = usePar ? par[idx] : own[idx];
            mmem += v;
            if (mmem > TH) { mmem -= TH; bits |= (1u << (half * 16 + tq)); }
        }
    }

    if (AmNext) {
        uint32_t cap = 0;
        #pragma unroll
        for (int t = 0; t < 32; ++t) {
            unsigned long long bal = __ballot((bits >> t) & 1u);
            if (lane == t) cap = (uint32_t)bal;   // lo32 = cols of this nw half
        }
        if (hi == 0)
            AmNext[(size_t)(batch * 32 + lr) * 32 + nTile * 2 + nw] = cap;
    } else if (hi == 0) {
        out[batch * 1024 + nBase + nw * 32 + lr] = (float)__popc(bits) * 0.03125f;
    }
}

// ---------------------------------------------------------------- launch ----
extern "C" void kernel_launch(void* const* d_in, const int* in_sizes, int n_in,
                              void* d_out, int out_size, void* d_ws, size_t ws_size,
                              hipStream_t stream) {
    const float* x  = (const float*)d_in[0];
    const float* w  = (const float*)d_in[1];
    const float* th = (const float*)d_in[2];
    float* out = (float*)d_out;
    char* ws = (char*)d_ws;

    signed char* planes = (signed char*)(ws);                 // 16 MB
    uint32_t*    Am0    = (uint32_t*)(ws + 16777216);         // 512 KB
    uint32_t*    Am1    = (uint32_t*)(ws + 17301504);         // 512 KB

    k_prep<<<4608, 256, 0, stream>>>(x, w, Am0, planes);

    uint32_t* Ain = Am0;
    uint32_t* Anx = Am1;
    for (int l = 0; l < 4; ++l) {
        k_fused<<<512, 512, 0, stream>>>(Ain, planes, th,
                                         (l < 3) ? Anx : nullptr,
                                         (l == 3) ? out : nullptr, l);
        uint32_t* tmp = Ain; Ain = Anx; Anx = tmp;
    }
}